// Round 10
// baseline (471.055 us; speedup 1.0000x reference)
//
#include <hip/hip_runtime.h>

// ---------------- problem constants ----------------
#define CCH   19
#define HWSZ  262144          // 512*512
#define NPIX  4194304         // 16*512*512
#define NMIN  262144
#define THRESH_F 0.35667494393873245f   // float32(-log(0.7))

#define NBLK  1024            // compute grid (4 blocks/CU)

// radix-select hist sizes on float bits: 11 + 11 + 10
#define NB1 2048
#define NB2 2048
#define NB3 1024

// ---------------- scalar CE for one pixel (fallback path only) -------------
__device__ __forceinline__ float ce_pixel(
    const float* __restrict__ inp, const int* __restrict__ tgt, unsigned p)
{
    const unsigned b  = p >> 18;
    const unsigned hw = p & (HWSZ - 1);
    const float* base = inp + (size_t)b * (CCH * HWSZ) + hw;
    const int t = tgt[p];
    float x[CCH];
    float m = -3.4e38f, xt = 0.f;
    #pragma unroll
    for (int c = 0; c < CCH; ++c) {
        float v = base[(size_t)c * HWSZ];
        x[c] = v;
        m = fmaxf(m, v);
        xt = (c == t) ? v : xt;
    }
    float s = 0.f;
    #pragma unroll
    for (int c = 0; c < CCH; ++c) s += __expf(x[c] - m);
    float l = (t != 255) ? (__logf(s) + m - xt) : 0.f;
    return fmaxf(l, 0.f);
}

// ---------------- kernel 1: CE + above-thresh sum/count + self-finalize ----
// Live path does NOTHING but read 335.6 MB, reduce, and (last block) write out.
__global__ __launch_bounds__(256) void k_compute4(
    const float* __restrict__ inp, const int* __restrict__ tgt,
    double* __restrict__ sumT, unsigned long long* __restrict__ cntT,
    unsigned int* __restrict__ arrival, float* __restrict__ out)
{
    float ls = 0.f;
    unsigned int lc = 0;
    const unsigned int stride = gridDim.x * 256;

    for (unsigned int i = blockIdx.x * 256 + threadIdx.x; i < NPIX / 4; i += stride) {
        const unsigned int p  = i * 4;            // first pixel of the group
        const unsigned int b  = p >> 18;          // group never spans a batch img
        const unsigned int hw = p & (HWSZ - 1);
        const float* base = inp + (size_t)b * (CCH * HWSZ) + hw;
        const int4 t4 = *(const int4*)(tgt + p);

        float4 x[CCH];
        float4 m  = make_float4(-3.4e38f, -3.4e38f, -3.4e38f, -3.4e38f);
        float4 xt = make_float4(0.f, 0.f, 0.f, 0.f);
        #pragma unroll
        for (int c = 0; c < CCH; ++c) {
            const float4 v = *(const float4*)(base + (size_t)c * HWSZ);
            x[c] = v;
            m.x = fmaxf(m.x, v.x); m.y = fmaxf(m.y, v.y);
            m.z = fmaxf(m.z, v.z); m.w = fmaxf(m.w, v.w);
            xt.x = (c == t4.x) ? v.x : xt.x;      // predicated, no runtime index
            xt.y = (c == t4.y) ? v.y : xt.y;
            xt.z = (c == t4.z) ? v.z : xt.z;
            xt.w = (c == t4.w) ? v.w : xt.w;
        }
        float4 s = make_float4(0.f, 0.f, 0.f, 0.f);
        #pragma unroll
        for (int c = 0; c < CCH; ++c) {
            s.x += __expf(x[c].x - m.x);
            s.y += __expf(x[c].y - m.y);
            s.z += __expf(x[c].z - m.z);
            s.w += __expf(x[c].w - m.w);
        }

        float4 l;
        l.x = (t4.x != 255) ? (__logf(s.x) + m.x - xt.x) : 0.f;
        l.y = (t4.y != 255) ? (__logf(s.y) + m.y - xt.y) : 0.f;
        l.z = (t4.z != 255) ? (__logf(s.z) + m.z - xt.z) : 0.f;
        l.w = (t4.w != 255) ? (__logf(s.w) + m.w - xt.w) : 0.f;
        l.x = fmaxf(l.x, 0.f); l.y = fmaxf(l.y, 0.f);
        l.z = fmaxf(l.z, 0.f); l.w = fmaxf(l.w, 0.f);

        if (l.x > THRESH_F) { ls += l.x; lc++; }
        if (l.y > THRESH_F) { ls += l.y; lc++; }
        if (l.z > THRESH_F) { ls += l.z; lc++; }
        if (l.w > THRESH_F) { ls += l.w; lc++; }
    }

    // block-reduce ls / lc (identical tree to prior rounds -> bit-identical out)
    #pragma unroll
    for (int off = 32; off > 0; off >>= 1) {
        ls += __shfl_down(ls, off);
        lc += __shfl_down(lc, off);
    }
    __shared__ float wsum[4];
    __shared__ unsigned int wcnt[4];
    const int lane = threadIdx.x & 63, wid = threadIdx.x >> 6;
    if (lane == 0) { wsum[wid] = ls; wcnt[wid] = lc; }
    __syncthreads();
    if (threadIdx.x == 0) {
        atomicAdd(sumT, (double)(wsum[0] + wsum[1] + wsum[2] + wsum[3]));
        atomicAdd(cntT, (unsigned long long)(wcnt[0] + wcnt[1] + wcnt[2] + wcnt[3]));
        __threadfence();                              // release partials
        const unsigned int old = atomicAdd(arrival, 1u);
        if (old == gridDim.x - 1) {                   // I am the last block
            __threadfence();                          // acquire all partials
            const unsigned long long c = atomicAdd(cntT, 0ull);
            const double sT = *(volatile double*)sumT;
            if (c > (unsigned long long)NMIN)
                out[0] = (float)(sT / (double)c);     // live path: done here
        }
    }
}

// ---------------- in-block radix-select helper -----------------------------
__device__ void block_select(
    unsigned int* cnt, unsigned int* psum, int nbins, unsigned int K,
    unsigned int* outB, unsigned int* outRem)
{
    const int tid = threadIdx.x;
    const int chunk = nbins >> 8;
    const int lo = tid * chunk, hi = lo + chunk;
    unsigned int s = 0;
    for (int b = lo; b < hi; ++b) s += cnt[b];
    psum[tid] = s;
    if (tid == 0) psum[256] = 0;
    __syncthreads();
    // inclusive suffix-sum (Hillis-Steele)
    for (int d = 1; d < 256; d <<= 1) {
        unsigned int v = psum[tid] + ((tid + d < 256) ? psum[tid + d] : 0);
        __syncthreads();
        psum[tid] = v;
        __syncthreads();
    }
    const unsigned int above = psum[tid + 1];
    if (psum[tid] >= K && above < K) {        // crossing is in my chunk
        unsigned int cum = above;
        for (int b = hi - 1; b >= lo; --b) {
            const unsigned int prev = cum;
            cum += cnt[b];
            if (cum >= K) { *outB = (unsigned int)b; *outRem = K - prev; break; }
        }
    }
    __syncthreads();
}

// ---------------- kernel 2: single-block fallback (dead when cntT>NMIN) ----
// Recomputes CE on the fly; hist -> select x3 -> sumtop, all in one block.
__global__ __launch_bounds__(256) void k_fallback(
    const float* __restrict__ inp, const int* __restrict__ tgt,
    const unsigned long long* __restrict__ cntT, float* __restrict__ out)
{
    if (*cntT > (unsigned long long)NMIN) return;   // live path handled by compute

    __shared__ unsigned int sh[NB1];
    __shared__ unsigned int psum[257];
    __shared__ unsigned int selB, selR;
    const int tid = threadIdx.x;

    // ---- level 1: top 11 bits ----
    for (int i = tid; i < NB1; i += 256) sh[i] = 0;
    __syncthreads();
    for (unsigned int p = tid; p < NPIX; p += 256) {
        const float l = ce_pixel(inp, tgt, p);
        atomicAdd(&sh[__float_as_uint(l) >> 21], 1u);
    }
    __syncthreads();
    block_select(sh, psum, NB1, NMIN, &selB, &selR);
    const unsigned int pref1 = selB;
    const unsigned int K2    = selR;

    // ---- level 2: next 11 bits ----
    for (int i = tid; i < NB2; i += 256) sh[i] = 0;
    __syncthreads();
    for (unsigned int p = tid; p < NPIX; p += 256) {
        const unsigned int bits = __float_as_uint(ce_pixel(inp, tgt, p));
        if ((bits >> 21) == pref1) atomicAdd(&sh[(bits >> 10) & 0x7FF], 1u);
    }
    __syncthreads();
    block_select(sh, psum, NB2, K2, &selB, &selR);
    const unsigned int pref2 = (pref1 << 11) | selB;
    const unsigned int K3    = selR;

    // ---- level 3: last 10 bits ----
    for (int i = tid; i < NB3; i += 256) sh[i] = 0;
    __syncthreads();
    for (unsigned int p = tid; p < NPIX; p += 256) {
        const unsigned int bits = __float_as_uint(ce_pixel(inp, tgt, p));
        if ((bits >> 10) == pref2) atomicAdd(&sh[bits & 0x3FF], 1u);
    }
    __syncthreads();
    block_select(sh, psum, NB3, K3, &selB, &selR);
    const unsigned int tb = (pref2 << 10) | selB;   // bit pattern of t
    __syncthreads();

    // ---- sum/count strictly above t ----
    float ls = 0.f;
    unsigned int lc = 0;
    for (unsigned int p = tid; p < NPIX; p += 256) {
        const float l = ce_pixel(inp, tgt, p);
        if (__float_as_uint(l) > tb) { ls += l; lc++; }
    }
    #pragma unroll
    for (int off = 32; off > 0; off >>= 1) {
        ls += __shfl_down(ls, off);
        lc += __shfl_down(lc, off);
    }
    __shared__ float fsum[4];
    __shared__ unsigned int fcnt[4];
    const int lane = tid & 63, wid = tid >> 6;
    if (lane == 0) { fsum[wid] = ls; fcnt[wid] = lc; }
    __syncthreads();
    if (tid == 0) {
        const double sG = (double)(fsum[0] + fsum[1] + fsum[2] + fsum[3]);
        const unsigned int cG = fcnt[0] + fcnt[1] + fcnt[2] + fcnt[3];
        const float t = __uint_as_float(tb);
        out[0] = (float)((sG + (double)(NMIN - cG) * (double)t) / (double)NMIN);
    }
}

// ---------------- launch ---------------------------------------------------
extern "C" void kernel_launch(void* const* d_in, const int* in_sizes, int n_in,
                              void* d_out, int out_size, void* d_ws, size_t ws_size,
                              hipStream_t stream)
{
    const float* inp = (const float*)d_in[0];
    const int*   tgt = (const int*)d_in[1];
    float*       out = (float*)d_out;
    char*        ws  = (char*)d_ws;

    double*             sumT    = (double*)(ws + 0);
    unsigned long long* cntT    = (unsigned long long*)(ws + 8);
    unsigned int*       arrival = (unsigned int*)(ws + 16);

    // zero the 3 accumulators (ws is poisoned 0xAA before every launch)
    hipMemsetAsync(ws, 0, 32, stream);

    // 1) CE + above-threshold sum/count; last block writes out when cond==true
    k_compute4<<<NBLK, 256, 0, stream>>>(inp, tgt, sumT, cntT, arrival, out);
    // 2) single-block exact fallback; instant exit when cond==true
    k_fallback<<<1, 256, 0, stream>>>(inp, tgt, cntT, out);
}